// Round 1
// baseline (421.613 us; speedup 1.0000x reference)
//
#include <hip/hip_runtime.h>
#include <math.h>

// Problem constants
#define NPIX   12544          // 64*14*14
#define CIN    2048
#define PPB    16             // pixels per block (kernel 1)
#define KSPLIT 512            // K-range per wave (4 waves * 512 = 2048)

// Kernel 1: per-pixel attention scalar a_p = sigmoid(MLP(x_p))
// block = 256 threads = 4 waves; lane = output channel n of layer 1 (64 ch).
// Wave wv handles K-slice [wv*512, wv*512+512). x reads are wave-uniform
// (s_load path); W1 reads are lane-coalesced and L2-resident (512 KB).
__global__ __launch_bounds__(256) void attn_scores(
    const float* __restrict__ x,
    const float* __restrict__ W1, const float* __restrict__ b1,
    const float* __restrict__ W2, const float* __restrict__ b2,
    const float* __restrict__ W3, const float* __restrict__ b3,
    const float* __restrict__ W4, const float* __restrict__ b4,
    float* __restrict__ a_out)
{
    __shared__ float part[4][PPB][64];   // 16 KB partial h1 per wave
    __shared__ float h1s[PPB][64];       // 4 KB  reduced h1 (post-relu)

    const int lane = threadIdx.x & 63;
    const int wv   = threadIdx.x >> 6;
    const size_t pix0 = (size_t)blockIdx.x * PPB;
    const float* xp = x + pix0 * CIN;

    float acc[PPB];
#pragma unroll
    for (int m = 0; m < PPB; ++m) acc[m] = 0.f;

    const int kbase = wv * KSPLIT;
    for (int k0 = kbase; k0 < kbase + KSPLIT; k0 += 4) {
        float w[4];
#pragma unroll
        for (int j = 0; j < 4; ++j)
            w[j] = W1[(size_t)(k0 + j) * 64 + lane];
#pragma unroll
        for (int j = 0; j < 4; ++j) {
#pragma unroll
            for (int m = 0; m < PPB; ++m)
                acc[m] = fmaf(xp[(size_t)m * CIN + k0 + j], w[j], acc[m]);
        }
    }

#pragma unroll
    for (int m = 0; m < PPB; ++m) part[wv][m][lane] = acc[m];
    __syncthreads();

    // Reduce 4 K-partials + bias + relu -> h1s. 1024 elems / 256 threads.
#pragma unroll
    for (int e = threadIdx.x; e < PPB * 64; e += 256) {
        const int m = e >> 6, n = e & 63;
        float v = part[0][m][n] + part[1][m][n] + part[2][m][n] + part[3][m][n]
                + b1[n];
        h1s[m][n] = fmaxf(v, 0.f);
    }
    __syncthreads();

    // Tiny MLP tail: 16 threads, one pixel each (~1.2 kFLOP each).
    if (threadIdx.x < PPB) {
        const int m = threadIdx.x;
        float h2[16];
#pragma unroll
        for (int j = 0; j < 16; ++j) {
            float s = b2[j];
#pragma unroll
            for (int n = 0; n < 64; ++n) s = fmaf(h1s[m][n], W2[n * 16 + j], s);
            h2[j] = fmaxf(s, 0.f);
        }
        float h3[8];
#pragma unroll
        for (int j = 0; j < 8; ++j) {
            float s = b3[j];
#pragma unroll
            for (int n = 0; n < 16; ++n) s = fmaf(h2[n], W3[n * 8 + j], s);
            h3[j] = fmaxf(s, 0.f);
        }
        float z = b4[0];
#pragma unroll
        for (int n = 0; n < 8; ++n) z = fmaf(h3[n], W4[n], z);
        a_out[pix0 + m] = 1.f / (1.f + expf(-z));
    }
}

// Kernel 2: out[b,c] = sum_p a[b,p]*x[b,p,c] / sum_p a[b,p]
// grid (4, 64), block 256; each thread owns 2 channels (float2 loads).
// a[b,p] is wave-uniform -> s_load; x is L3-resident after kernel 1.
__global__ __launch_bounds__(256) void attn_gap(
    const float* __restrict__ x,
    const float* __restrict__ a,
    float* __restrict__ out)
{
    const int b  = blockIdx.y;                                  // 0..63
    const int c0 = (blockIdx.x * 256 + threadIdx.x) * 2;        // 0..2046
    const float* xb = x + (size_t)b * 196 * CIN + c0;
    const float* ab = a + b * 196;

    float s0 = 0.f, s1 = 0.f, asum = 0.f;
    for (int p = 0; p < 196; ++p) {
        const float ap = ab[p];                 // wave-uniform
        const float2 v = *(const float2*)(xb + (size_t)p * CIN);
        s0 = fmaf(ap, v.x, s0);
        s1 = fmaf(ap, v.y, s1);
        asum += ap;
    }
    const float inv = 1.f / asum;
    out[(size_t)b * CIN + c0]     = s0 * inv;
    out[(size_t)b * CIN + c0 + 1] = s1 * inv;
}

extern "C" void kernel_launch(void* const* d_in, const int* in_sizes, int n_in,
                              void* d_out, int out_size, void* d_ws, size_t ws_size,
                              hipStream_t stream)
{
    const float* x  = (const float*)d_in[0];
    const float* W1 = (const float*)d_in[1];
    const float* b1 = (const float*)d_in[2];
    const float* W2 = (const float*)d_in[3];
    const float* b2 = (const float*)d_in[4];
    const float* W3 = (const float*)d_in[5];
    const float* b3 = (const float*)d_in[6];
    const float* W4 = (const float*)d_in[7];
    const float* b4 = (const float*)d_in[8];
    float* out = (float*)d_out;

    float* a = (float*)d_ws;   // 12544 floats = 50 KB scratch

    attn_scores<<<NPIX / PPB, 256, 0, stream>>>(x, W1, b1, W2, b2, W3, b3, W4, b4, a);
    attn_gap<<<dim3(4, 64), 256, 0, stream>>>(x, a, out);
}

// Round 2
// 197.402 us; speedup vs baseline: 2.1358x; 2.1358x over previous
//
#include <hip/hip_runtime.h>
#include <math.h>

// ---- problem constants ----
#define NPIX 12544            // 64*14*14 pixels
#define CIN  2048
#define NB   64               // batch
#define PPIX 196              // pixels per batch image

typedef short  bf16x8 __attribute__((ext_vector_type(8)));
typedef float  f32x4  __attribute__((ext_vector_type(4)));

__device__ inline unsigned short f2bf(float f) {
    // round-to-nearest-even fp32 -> bf16 (inputs are well-behaved, no NaN)
    unsigned int u = __float_as_uint(f);
    u = (u + 0x7fffu + ((u >> 16) & 1u)) >> 16;
    return (unsigned short)u;
}

// ---- kernel 0: transpose+convert W1 [2048][64] f32 -> W1t [64][2048] bf16 ----
__global__ __launch_bounds__(256) void conv_w1(
    const float* __restrict__ W1, unsigned short* __restrict__ W1t)
{
    const int id = blockIdx.x * 256 + threadIdx.x;   // 0..131071
    const int n = id >> 11;                          // out channel 0..63
    const int k = id & 2047;                         // k 0..2047
    W1t[id] = f2bf(W1[k * 64 + n]);                  // write coalesced
}

// ---- kernel 1: a_p = sigmoid(MLP(x_p)) via bf16 MFMA layer-1 GEMM ----
// 1 wave/block, 16 pixels/block, 784 blocks. Wave computes 16x64 h1 tile
// with 4x mfma_f32_16x16x32_bf16 per K-step of 32 (64 steps), then 16 lanes
// run the 64->16->8->1 tail from LDS.
__global__ __launch_bounds__(64) void attn_scores_mfma(
    const float* __restrict__ x, const unsigned short* __restrict__ W1t,
    const float* __restrict__ b1,
    const float* __restrict__ W2, const float* __restrict__ b2,
    const float* __restrict__ W3, const float* __restrict__ b3,
    const float* __restrict__ W4, const float* __restrict__ b4,
    float* __restrict__ a_out)
{
    __shared__ float h1s[16][68];        // +4 pad: 2-way LDS conflicts only

    const int lane = threadIdx.x;        // 0..63
    const int l15  = lane & 15;          // A-row (pixel) / B-col (channel)
    const int q    = lane >> 4;          // k-quad 0..3
    const size_t pix0 = (size_t)blockIdx.x * 16;

    // A: lane reads x[pix0+l15][k0 + q*8 .. +8) as 2x float4, cvt to bf16
    const float* xr = x + (pix0 + l15) * (size_t)CIN + q * 8;
    // B: lane reads W1t[ct*16+l15][k0 + q*8 .. +8) as 16B (already bf16)
    const unsigned short* wr = W1t + (size_t)l15 * CIN + q * 8;

    f32x4 acc[4] = {{0,0,0,0},{0,0,0,0},{0,0,0,0},{0,0,0,0}};

#pragma unroll 2
    for (int k0 = 0; k0 < CIN; k0 += 32) {
        float4 xa = *(const float4*)(xr + k0);
        float4 xb = *(const float4*)(xr + k0 + 4);
        bf16x8 af;
        af[0] = (short)f2bf(xa.x); af[1] = (short)f2bf(xa.y);
        af[2] = (short)f2bf(xa.z); af[3] = (short)f2bf(xa.w);
        af[4] = (short)f2bf(xb.x); af[5] = (short)f2bf(xb.y);
        af[6] = (short)f2bf(xb.z); af[7] = (short)f2bf(xb.w);
#pragma unroll
        for (int ct = 0; ct < 4; ++ct) {
            bf16x8 bfr = *(const bf16x8*)(wr + (size_t)ct * 16 * CIN + k0);
            acc[ct] = __builtin_amdgcn_mfma_f32_16x16x32_bf16(af, bfr, acc[ct], 0, 0, 0);
        }
    }

    // C/D layout: col = lane&15 (channel-in-tile), row = q*4 + reg (pixel)
#pragma unroll
    for (int ct = 0; ct < 4; ++ct) {
        const float bias = b1[ct * 16 + l15];
#pragma unroll
        for (int r = 0; r < 4; ++r)
            h1s[q * 4 + r][ct * 16 + l15] = fmaxf(acc[ct][r] + bias, 0.f);
    }
    __syncthreads();

    // tail: 16 lanes, one pixel each
    if (lane < 16) {
        float hv[64];
#pragma unroll
        for (int i = 0; i < 16; ++i) {
            float4 t = *(const float4*)&h1s[lane][i * 4];
            hv[i*4+0] = t.x; hv[i*4+1] = t.y; hv[i*4+2] = t.z; hv[i*4+3] = t.w;
        }
        float h2[16];
#pragma unroll
        for (int j = 0; j < 16; ++j) {
            float s = b2[j];
#pragma unroll
            for (int k = 0; k < 64; ++k) s = fmaf(hv[k], W2[k * 16 + j], s);
            h2[j] = fmaxf(s, 0.f);
        }
        float h3[8];
#pragma unroll
        for (int j = 0; j < 8; ++j) {
            float s = b3[j];
#pragma unroll
            for (int k = 0; k < 16; ++k) s = fmaf(h2[k], W3[k * 8 + j], s);
            h3[j] = fmaxf(s, 0.f);
        }
        float z = b4[0];
#pragma unroll
        for (int k = 0; k < 8; ++k) z = fmaf(h3[k], W4[k], z);
        a_out[pix0 + lane] = 1.f / (1.f + expf(-z));
    }
}

// ---- kernel 2: partial weighted sums. grid (2 c-half, 64 b, 2 p-half) ----
// thread owns 4 channels (float4); 2 interleaved accumulators break the
// dependent-FMA chain; 256 blocks cover all CUs.
__global__ __launch_bounds__(256) void gap_partial(
    const float* __restrict__ x, const float* __restrict__ a,
    float* __restrict__ part)
{
    const int b  = blockIdx.y;
    const int pz = blockIdx.z;                       // 0..1 (98 pixels each)
    const int c0 = (blockIdx.x * 256 + threadIdx.x) * 4;
    const float* xb = x + ((size_t)b * PPIX + pz * 98) * CIN + c0;
    const float* ab = a + b * PPIX + pz * 98;

    float4 s0 = {0,0,0,0}, s1 = {0,0,0,0};
#pragma unroll 4
    for (int p = 0; p < 98; p += 2) {
        const float a0 = ab[p], a1 = ab[p + 1];
        const float4 v0 = *(const float4*)(xb + (size_t)p * CIN);
        const float4 v1 = *(const float4*)(xb + (size_t)(p + 1) * CIN);
        s0.x = fmaf(a0, v0.x, s0.x); s0.y = fmaf(a0, v0.y, s0.y);
        s0.z = fmaf(a0, v0.z, s0.z); s0.w = fmaf(a0, v0.w, s0.w);
        s1.x = fmaf(a1, v1.x, s1.x); s1.y = fmaf(a1, v1.y, s1.y);
        s1.z = fmaf(a1, v1.z, s1.z); s1.w = fmaf(a1, v1.w, s1.w);
    }
    float4 r;
    r.x = s0.x + s1.x; r.y = s0.y + s1.y; r.z = s0.z + s1.z; r.w = s0.w + s1.w;
    *(float4*)(part + ((size_t)pz * NB + b) * CIN + c0) = r;
}

// ---- kernel 3: finalize. grid 64 (one per b), block 512. ----
__global__ __launch_bounds__(512) void gap_final(
    const float* __restrict__ a, const float* __restrict__ part,
    float* __restrict__ out)
{
    __shared__ float red[512];
    const int b = blockIdx.x, t = threadIdx.x;
    red[t] = (t < PPIX) ? a[b * PPIX + t] : 0.f;
    __syncthreads();
#pragma unroll
    for (int s = 256; s > 0; s >>= 1) {
        if (t < s) red[t] += red[t + s];
        __syncthreads();
    }
    const float inv = 1.f / red[0];
    const int c0 = t * 4;
    const float4 p0 = *(const float4*)(part + ((size_t)0 * NB + b) * CIN + c0);
    const float4 p1 = *(const float4*)(part + ((size_t)1 * NB + b) * CIN + c0);
    float4 r;
    r.x = (p0.x + p1.x) * inv; r.y = (p0.y + p1.y) * inv;
    r.z = (p0.z + p1.z) * inv; r.w = (p0.w + p1.w) * inv;
    *(float4*)(out + (size_t)b * CIN + c0) = r;
}

extern "C" void kernel_launch(void* const* d_in, const int* in_sizes, int n_in,
                              void* d_out, int out_size, void* d_ws, size_t ws_size,
                              hipStream_t stream)
{
    const float* x  = (const float*)d_in[0];
    const float* W1 = (const float*)d_in[1];
    const float* b1 = (const float*)d_in[2];
    const float* W2 = (const float*)d_in[3];
    const float* b2 = (const float*)d_in[4];
    const float* W3 = (const float*)d_in[5];
    const float* b3 = (const float*)d_in[6];
    const float* W4 = (const float*)d_in[7];
    const float* b4 = (const float*)d_in[8];
    float* out = (float*)d_out;

    // ws layout: W1t bf16 [64][2048] @0 (256KB) | a f32 [12544] @256KB |
    //            part f32 [2][64][2048] @512KB (1MB). Total 1.5 MB.
    unsigned short* W1t = (unsigned short*)d_ws;
    float* a    = (float*)((char*)d_ws + (256 << 10));
    float* part = (float*)((char*)d_ws + (512 << 10));

    conv_w1<<<512, 256, 0, stream>>>(W1, W1t);
    attn_scores_mfma<<<NPIX / 16, 64, 0, stream>>>(x, W1t, b1, W2, b2, W3, b3, W4, b4, a);
    gap_partial<<<dim3(2, NB, 2), 256, 0, stream>>>(x, a, part);
    gap_final<<<NB, 512, 0, stream>>>(a, part, out);
}